// Round 9
// baseline (203.818 us; speedup 1.0000x reference)
//
#include <hip/hip_runtime.h>
#include <hip/hip_bf16.h>

// B=2, S=2048, D=1024, H=16, DK=64, THETA=10000
// Inputs fp32 (positions int32): x[2,2048,1024], token_positions[2048],
// Wq,Wk,Wv,Wo [1024,1024].  Output fp32 [2,2048,1024].
// proj: y[b,s,o] = sum_d x[b,s,d] * W[o,d]

typedef __attribute__((ext_vector_type(8))) short short8;   // 8 bf16 = 4 VGPRs
typedef __attribute__((ext_vector_type(4))) float floatx4;  // MFMA accumulator

static __device__ __forceinline__ unsigned short f2bf(float f) {
  __hip_bfloat16 h = __float2bfloat16(f);
  return *(unsigned short*)&h;
}

// pack 2 floats -> 2 bf16 in one u32 (half-up rounding + v_perm byte pick).
// low ushort = bf16(a), high ushort = bf16(b). Finite inputs only.
static __device__ __forceinline__ unsigned int pk2bf(float a, float b) {
  unsigned int ua = __float_as_uint(a) + 0x8000u;
  unsigned int ub = __float_as_uint(b) + 0x8000u;
  return __builtin_amdgcn_perm(ub, ua, 0x07060302u);
}

#if __has_builtin(__builtin_amdgcn_exp2f)
#define EXP2F(x) __builtin_amdgcn_exp2f(x)
#else
#define EXP2F(x) exp2f(x)
#endif

// async global->LDS DMA, 16 B per lane; lds base must be wave-uniform,
// HW writes lane i at ldsbase + i*16.
static __device__ __forceinline__ void gl2lds16(const unsigned short* g,
                                                unsigned short* l) {
  __builtin_amdgcn_global_load_lds(
      (const __attribute__((address_space(1))) void*)g,
      (__attribute__((address_space(3))) void*)l, 16, 0, 0);
}

// ---------------------------------------------------------------------------
// fp32 -> bf16 conversion for all 5 tensors + RoPE table gen, one launch.
// blockIdx.y: 0=x 1=Wq 2=Wk 3=Wv 4=Wo 5=rope tables
// ---------------------------------------------------------------------------
__global__ __launch_bounds__(256) void cvt_all(
    const float4* __restrict__ x,  const float4* __restrict__ wq,
    const float4* __restrict__ wk, const float4* __restrict__ wv,
    const float4* __restrict__ wo,
    ushort4* __restrict__ xb,  ushort4* __restrict__ wqb,
    ushort4* __restrict__ wkb, ushort4* __restrict__ wvb,
    ushort4* __restrict__ wob,
    const int* __restrict__ tokpos,
    float* __restrict__ ctab, float* __restrict__ stab) {
  int t = blockIdx.y;
  int i = blockIdx.x * 256 + threadIdx.x;
  if (t == 5) {
    if (i < 65536) {     // 2048 positions x 32 pair-freqs
      int s = i >> 5, f = i & 31;
      float inv = expf(-9.210340371976184f * (float)(2 * f) / 64.0f);
      float ang = (float)tokpos[s] * inv;
      ctab[i] = cosf(ang);
      stab[i] = sinf(ang);
    }
    return;
  }
  const float4* s = (t == 0) ? x : (t == 1) ? wq : (t == 2) ? wk : (t == 3) ? wv : wo;
  ushort4* d = (t == 0) ? xb : (t == 1) ? wqb : (t == 2) ? wkb : (t == 3) ? wvb : wob;
  int n4 = (t == 0) ? 1048576 : 262144;
  if (i < n4) {
    float4 v = s[i];
    ushort4 o;
    o.x = f2bf(v.x); o.y = f2bf(v.y); o.z = f2bf(v.z); o.w = f2bf(v.w);
    d[i] = o;
  }
}

// ---------------------------------------------------------------------------
// 128x128-tile GEMM body, m97 structure: global_load_lds width=16 staging into
// UNPADDED [128][64] LDS tiles with XOR chunk swizzle (LDS[r][c] holds global
// chunk c^(r&7); fragment reads fetch chunk (4ks+quad)^(l15&7) -> conflict-free
// per R7 measurement). C[128][128] = A[128x1024] * W^T, both row-major.
// ---------------------------------------------------------------------------
#define GEMM128_BODY(Aptr, Wptr, m0, n0)                                        \
  __shared__ __align__(16) unsigned short lA[128 * 64];                         \
  __shared__ __align__(16) unsigned short lB[128 * 64];                         \
  int tid = threadIdx.x;                                                        \
  int wave = tid >> 6, lane = tid & 63;                                         \
  int wm = wave >> 1, wn = wave & 1;                                            \
  int l15 = lane & 15, quad = lane >> 4;                                        \
  int srow = wave * 32 + (lane >> 3);  /* staging row (+p*8) */                 \
  int sch = lane & 7;                  /* staging 16B-chunk  */                 \
  int fsw = l15 & 7;                   /* fragment-read swizzle */              \
  floatx4 acc[4][4];                                                            \
  _Pragma("unroll") for (int m = 0; m < 4; ++m)                                 \
      _Pragma("unroll") for (int n = 0; n < 4; ++n)                             \
          acc[m][n] = (floatx4){0.f, 0.f, 0.f, 0.f};                            \
  for (int kt = 0; kt < 16; ++kt) {                                             \
    _Pragma("unroll") for (int p = 0; p < 4; ++p) {                             \
      int r = srow + p * 8;                                                     \
      int g = sch ^ (r & 7);                                                    \
      gl2lds16(Aptr + (size_t)(m0 + r) * 1024 + kt * 64 + g * 8,                \
               lA + (wave * 32 + p * 8) * 64);                                  \
      gl2lds16(Wptr + (size_t)(n0 + r) * 1024 + kt * 64 + g * 8,                \
               lB + (wave * 32 + p * 8) * 64);                                  \
    }                                                                           \
    __syncthreads();                                                            \
    _Pragma("unroll") for (int ks = 0; ks < 2; ++ks) {                          \
      short8 af[4], bf[4];                                                      \
      _Pragma("unroll") for (int m = 0; m < 4; ++m)                             \
          af[m] = *(const short8*)(lA + (wm * 64 + m * 16 + l15) * 64 +         \
                                   (((ks * 4 + quad) ^ fsw) * 8));              \
      _Pragma("unroll") for (int n = 0; n < 4; ++n)                             \
          bf[n] = *(const short8*)(lB + (wn * 64 + n * 16 + l15) * 64 +         \
                                   (((ks * 4 + quad) ^ fsw) * 8));              \
      _Pragma("unroll") for (int m = 0; m < 4; ++m)                             \
          _Pragma("unroll") for (int n = 0; n < 4; ++n)                         \
              acc[m][n] = __builtin_amdgcn_mfma_f32_16x16x32_bf16(              \
                  af[m], bf[n], acc[m][n], 0, 0, 0);                            \
    }                                                                           \
    __syncthreads();                                                            \
  }

// ---------------------------------------------------------------------------
// QKV projection, tiled MFMA GEMM + fused RoPE epilogue.
// Q pre-scaled by (1/sqrt(64))*log2(e) so attention can use exp2 directly.
// Q,K bf16 [bh][s][64]; V transposed [bh][d][2048].
// ---------------------------------------------------------------------------
__global__ __launch_bounds__(256) void qkv_mfma(
    const unsigned short* __restrict__ X,
    const unsigned short* __restrict__ Wq,
    const unsigned short* __restrict__ Wk,
    const unsigned short* __restrict__ Wv,
    const float* __restrict__ ctab, const float* __restrict__ stab,
    unsigned short* __restrict__ Qo, unsigned short* __restrict__ Ko,
    unsigned short* __restrict__ Vo) {
  int mat = blockIdx.z;  // 0=q 1=k 2=v
  const unsigned short* W = (mat == 0) ? Wq : ((mat == 1) ? Wk : Wv);
  unsigned short* Out = (mat == 0) ? Qo : ((mat == 1) ? Ko : Vo);
  int m0 = blockIdx.x * 128, n0 = blockIdx.y * 128;

  GEMM128_BODY(X, W, m0, n0)

#pragma unroll
  for (int n = 0; n < 4; ++n) {
    int col = n0 + wn * 64 + n * 16 + l15;  // 0..1023
    int h = col >> 6;
    int d = col & 63;
    int pi = d >> 1;
    bool odd = (d & 1) != 0;
    size_t hb = (size_t)h * 2048 * 64;
#pragma unroll
    for (int m = 0; m < 4; ++m) {
      int row0 = m0 + wm * 64 + m * 16 + quad * 4;  // rows row0..row0+3
      int b = row0 >> 11;
      int s0 = row0 & 2047;
      size_t base = (size_t)b * 16 * 2048 * 64 + hb;
      if (mat == 2) {
        // V: packed b64 store along s (transposed layout [d][s])
        ushort4 pv;
        pv.x = f2bf(acc[m][n][0]);
        pv.y = f2bf(acc[m][n][1]);
        pv.z = f2bf(acc[m][n][2]);
        pv.w = f2bf(acc[m][n][3]);
        *(ushort4*)(Out + base + (size_t)d * 2048 + s0) = pv;
      } else {
#pragma unroll
        for (int i = 0; i < 4; ++i) {
          int s = s0 + i;
          float v = acc[m][n][i];
          float p = __shfl_xor(v, 1);
          float c = ctab[s * 32 + pi];
          float sn = stab[s * 32 + pi];
          float res = odd ? fmaf(p, sn, v * c) : fmaf(v, c, -p * sn);
          if (mat == 0) res *= 0.1803368801111204f;  // 0.125 * log2(e)
          Out[base + (size_t)s * 64 + d] = f2bf(res);
        }
      }
    }
  }
}

// ---------------------------------------------------------------------------
// Output projection: out = Oc @ Wo^T, tiled MFMA GEMM, fp32 store
// ---------------------------------------------------------------------------
__global__ __launch_bounds__(256) void oproj_mfma(
    const unsigned short* __restrict__ A, const unsigned short* __restrict__ Wo,
    float* __restrict__ Out) {
  int m0 = blockIdx.x * 128, n0 = blockIdx.y * 128;

  GEMM128_BODY(A, Wo, m0, n0)

#pragma unroll
  for (int m = 0; m < 4; ++m) {
#pragma unroll
    for (int n = 0; n < 4; ++n) {
      int col = n0 + wn * 64 + n * 16 + l15;
#pragma unroll
      for (int i = 0; i < 4; ++i) {
        int row = m0 + wm * 64 + m * 16 + quad * 4 + i;
        Out[(size_t)row * 1024 + col] = acc[m][n][i];
      }
    }
  }
}

// ---------------------------------------------------------------------------
// Flash attention v3: 2 waves/block (128 thr), 32 q per wave (2 q-subtiles
// share every K/V fragment read -> LDS reads per q halved vs 16q/wave).
// Transposed-score form: per-lane q softmax (in-lane tree + 2 shfl_xor).
// K/V LDS: unpadded stride-64 with XOR chunk swizzle (conflict-free, R8).
// Softmax in log2 domain (Q pre-scaled by 0.125*log2e) -> raw v_exp_f32.
// bf16 packing via v_perm half-up rounding (1 instr per 2 values).
// Register-prefetch double buffering for K/V staging.
// Balance swizzle: co-resident blocks {id,id+256,id+512,id+768} get qtiles
// {x, 31-x, (15-x)&31, (16+x)&31} -> 66 tile-iters per CU for every x.
// ---------------------------------------------------------------------------
#define LPS 72  // lP row stride

__global__ __launch_bounds__(128, 2) void attn_flash(
    const unsigned short* __restrict__ Q, const unsigned short* __restrict__ K,
    const unsigned short* __restrict__ Vt, unsigned short* __restrict__ Oc) {
  __shared__ __align__(16) unsigned short lK[64 * 64];   // [kj][d] swizzled
  __shared__ __align__(16) unsigned short lV[64 * 64];   // [d][kj] swizzled
  __shared__ unsigned short lP[2][32 * LPS];             // per-wave [q][kj]

  int tid = threadIdx.x;
  int wave = tid >> 6, lane = tid & 63;
  int l15 = lane & 15, quad = lane >> 4;

  int xb_ = blockIdx.x;          // 0..31
  int yb_ = blockIdx.y;          // 0..31
  int jb = yb_ >> 3, ib = yb_ & 7;
  int qtile;
  if (jb == 0)      qtile = xb_;
  else if (jb == 1) qtile = 31 - xb_;
  else if (jb == 2) qtile = (15 - xb_) & 31;
  else              qtile = (16 + xb_) & 31;
  int bh = ib * 4 + jb;

  size_t base = (size_t)bh * 2048 * 64;
  int qbase = qtile * 64;

  // Q fragments: q = qbase + wave*32 + qs*16 + l15
  short8 qb[2][2];
#pragma unroll
  for (int qs = 0; qs < 2; ++qs) {
    const unsigned short* qrow =
        Q + base + (size_t)(qbase + wave * 32 + qs * 16 + l15) * 64;
    qb[qs][0] = *(const short8*)(qrow + quad * 8);
    qb[qs][1] = *(const short8*)(qrow + 32 + quad * 8);
  }

  floatx4 o[2][4];               // O^T[d = n*16+quad*4+reg][q]
  float m_i[2], l_i[2];          // per-lane softmax state (q = qs,l15)
#pragma unroll
  for (int qs = 0; qs < 2; ++qs) {
    m_i[qs] = -1e30f;
    l_i[qs] = 0.f;
#pragma unroll
    for (int n = 0; n < 4; ++n) o[qs][n] = (floatx4){0.f, 0.f, 0.f, 0.f};
  }

  // staging: 128 threads cover rows r0+16r (r=0..3), chunk g; XOR swizzle
  int r0 = tid >> 3, g = tid & 7;
  int e0 = g * 8;                       // global chunk offset (elements)
  int sl = (g ^ (r0 & 7)) * 8;          // swizzled LDS slot ( (r+16k)&7 == r&7 )
  int fsw = l15 & 7;                    // fragment-read swizzle
  int c0 = (quad ^ fsw) * 8;            // slot of global chunk quad
  int c1 = ((quad + 4) ^ fsw) * 8;      // slot of global chunk quad+4

  // prefetch kt=0
  short8 pk[4], pv[4];
  {
    const unsigned short* kp = K + base;
    const unsigned short* vp = Vt + base;
#pragma unroll
    for (int r = 0; r < 4; ++r) {
      pk[r] = *(const short8*)(kp + (r0 + r * 16) * 64 + e0);
      pv[r] = *(const short8*)(vp + (size_t)(r0 + r * 16) * 2048 + e0);
    }
  }

  for (int kt = 0; kt <= qtile; ++kt) {
    __syncthreads();   // all waves done reading lK/lV from previous iter
#pragma unroll
    for (int r = 0; r < 4; ++r) {
      *(short8*)(lK + (r0 + r * 16) * 64 + sl) = pk[r];
      *(short8*)(lV + (r0 + r * 16) * 64 + sl) = pv[r];
    }
    __syncthreads();

    if (kt < qtile) {  // prefetch next tile
      const unsigned short* kn = K + base + (size_t)(kt + 1) * 4096;
      const unsigned short* vn = Vt + base + (kt + 1) * 64;
#pragma unroll
      for (int r = 0; r < 4; ++r) {
        pk[r] = *(const short8*)(kn + (r0 + r * 16) * 64 + e0);
        pv[r] = *(const short8*)(vn + (size_t)(r0 + r * 16) * 2048 + e0);
      }
    }

    // ---- S^T = K·Q^T : sc[qs][sub][i] = score(kpos=sub*16+quad*4+i, q)
    float sc[2][4][4];
#pragma unroll
    for (int sub = 0; sub < 4; ++sub) {
      const unsigned short* kr = lK + (sub * 16 + l15) * 64;
      short8 a0 = *(const short8*)(kr + c0);
      short8 a1 = *(const short8*)(kr + c1);
#pragma unroll
      for (int qs = 0; qs < 2; ++qs) {
        floatx4 s = {0.f, 0.f, 0.f, 0.f};
        s = __builtin_amdgcn_mfma_f32_16x16x32_bf16(a0, qb[qs][0], s, 0, 0, 0);
        s = __builtin_amdgcn_mfma_f32_16x16x32_bf16(a1, qb[qs][1], s, 0, 0, 0);
#pragma unroll
        for (int i = 0; i < 4; ++i) sc[qs][sub][i] = s[i];
      }
    }

    // ---- causal mask (diagonal tile only)
    if (kt == qtile) {
#pragma unroll
      for (int qs = 0; qs < 2; ++qs) {
        int qin = wave * 32 + qs * 16 + l15;
#pragma unroll
        for (int sub = 0; sub < 4; ++sub)
#pragma unroll
          for (int i = 0; i < 4; ++i)
            if (sub * 16 + quad * 4 + i > qin) sc[qs][sub][i] = -1e30f;
      }
    }

    // ---- online softmax (log2 domain) + P write, per q-subtile
#pragma unroll
    for (int qs = 0; qs < 2; ++qs) {
      float mb = sc[qs][0][0];
#pragma unroll
      for (int sub = 0; sub < 4; ++sub)
#pragma unroll
        for (int i = 0; i < 4; ++i) mb = fmaxf(mb, sc[qs][sub][i]);
      mb = fmaxf(mb, __shfl_xor(mb, 16));
      mb = fmaxf(mb, __shfl_xor(mb, 32));

      float mn = fmaxf(m_i[qs], mb);
      float al = EXP2F(m_i[qs] - mn);
      m_i[qs] = mn;
      float rs = 0.f;
#pragma unroll
      for (int sub = 0; sub < 4; ++sub)
#pragma unroll
        for (int i = 0; i < 4; ++i) {
          float p = EXP2F(sc[qs][sub][i] - mn);
          sc[qs][sub][i] = p;
          rs += p;
        }
      rs += __shfl_xor(rs, 16);
      rs += __shfl_xor(rs, 32);
      l_i[qs] = l_i[qs] * al + rs;

#pragma unroll
      for (int n = 0; n < 4; ++n) {
        o[qs][n][0] *= al; o[qs][n][1] *= al;
        o[qs][n][2] *= al; o[qs][n][3] *= al;
      }

      // P^T -> lP rows [q][k], packed pairs via v_perm
      unsigned short* pw = lP[wave] + (qs * 16 + l15) * LPS;
#pragma unroll
      for (int sub = 0; sub < 4; ++sub) {
        uint2 w;
        w.x = pk2bf(sc[qs][sub][0], sc[qs][sub][1]);
        w.y = pk2bf(sc[qs][sub][2], sc[qs][sub][3]);
        *(uint2*)(pw + sub * 16 + quad * 4) = w;
      }
    }

    // ---- P fragments (B-operand), then O^T += V^T·P^T (V reads shared by qs)
    short8 pa[2][2];
#pragma unroll
    for (int qs = 0; qs < 2; ++qs) {
      const unsigned short* pr = lP[wave] + (qs * 16 + l15) * LPS + quad * 8;
      pa[qs][0] = *(const short8*)(pr);
      pa[qs][1] = *(const short8*)(pr + 32);
    }
#pragma unroll
    for (int n = 0; n < 4; ++n) {
      const unsigned short* vr = lV + (n * 16 + l15) * 64;
      short8 vb0 = *(const short8*)(vr + c0);
      short8 vb1 = *(const short8*)(vr + c1);
#pragma unroll
      for (int qs = 0; qs < 2; ++qs) {
        o[qs][n] = __builtin_amdgcn_mfma_f32_16x16x32_bf16(vb0, pa[qs][0], o[qs][n], 0, 0, 0);
        o[qs][n] = __builtin_amdgcn_mfma_f32_16x16x32_bf16(vb1, pa[qs][1], o[qs][n], 0, 0, 0);
      }
    }
  }

  // ---- epilogue: per-lane 1/l, packed b64 stores
  int b = bh >> 4, h = bh & 15;
#pragma unroll
  for (int qs = 0; qs < 2; ++qs) {
    float inv = 1.f / l_i[qs];
    int s = qbase + wave * 32 + qs * 16 + l15;
    size_t orow = (size_t)(b * 2048 + s) * 1024 + h * 64;
#pragma unroll
    for (int n = 0; n < 4; ++n) {
      uint2 ov;
      ov.x = pk2bf(o[qs][n][0] * inv, o[qs][n][1] * inv);
      ov.y = pk2bf(o[qs][n][2] * inv, o[qs][n][3] * inv);
      *(uint2*)(Oc + orow + n * 16 + quad * 4) = ov;
    }
  }
}

// ---------------------------------------------------------------------------
extern "C" void kernel_launch(void* const* d_in, const int* in_sizes, int n_in,
                              void* d_out, int out_size, void* d_ws, size_t ws_size,
                              hipStream_t stream) {
  const float* x  = (const float*)d_in[0];
  const int* tokpos = (const int*)d_in[1];
  const float* Wq = (const float*)d_in[2];
  const float* Wk = (const float*)d_in[3];
  const float* Wv = (const float*)d_in[4];
  const float* Wo = (const float*)d_in[5];
  float* out = (float*)d_out;

  float* ws = (float*)d_ws;
  float* ctab = ws;
  float* stab = ctab + 65536;
  unsigned short* u = (unsigned short*)(stab + 65536);
  unsigned short* Qb  = u;
  unsigned short* Kb  = Qb + 4194304;
  unsigned short* Vb  = Kb + 4194304;   // transposed [bh][d][s]
  unsigned short* Oc  = Vb + 4194304;
  unsigned short* xb  = Oc + 4194304;
  unsigned short* Wqb = xb + 4194304;
  unsigned short* Wkb = Wqb + 1048576;
  unsigned short* Wvb = Wkb + 1048576;
  unsigned short* Wob = Wvb + 1048576;

  cvt_all<<<dim3(4096, 6), 256, 0, stream>>>(
      (const float4*)x, (const float4*)Wq, (const float4*)Wk,
      (const float4*)Wv, (const float4*)Wo,
      (ushort4*)xb, (ushort4*)Wqb, (ushort4*)Wkb, (ushort4*)Wvb, (ushort4*)Wob,
      tokpos, ctab, stab);

  qkv_mfma<<<dim3(32, 8, 3), 256, 0, stream>>>(
      xb, Wqb, Wkb, Wvb, ctab, stab, Qb, Kb, Vb);
  attn_flash<<<dim3(32, 32), 128, 0, stream>>>(Qb, Kb, Vb, Oc);
  oproj_mfma<<<dim3(32, 8), 256, 0, stream>>>(Oc, Wob, out);
}

// Round 10
// 190.392 us; speedup vs baseline: 1.0705x; 1.0705x over previous
//
#include <hip/hip_runtime.h>
#include <hip/hip_bf16.h>

// B=2, S=2048, D=1024, H=16, DK=64, THETA=10000
// Inputs fp32 (positions int32): x[2,2048,1024], token_positions[2048],
// Wq,Wk,Wv,Wo [1024,1024].  Output fp32 [2,2048,1024].
// proj: y[b,s,o] = sum_d x[b,s,d] * W[o,d]

typedef __attribute__((ext_vector_type(8))) short short8;   // 8 bf16 = 4 VGPRs
typedef __attribute__((ext_vector_type(4))) float floatx4;  // MFMA accumulator

static __device__ __forceinline__ unsigned short f2bf(float f) {
  __hip_bfloat16 h = __float2bfloat16(f);
  return *(unsigned short*)&h;
}

// pack 2 floats -> 2 bf16 in one u32 (half-up rounding + v_perm byte pick).
// low ushort = bf16(a), high ushort = bf16(b). Finite inputs only.
static __device__ __forceinline__ unsigned int pk2bf(float a, float b) {
  unsigned int ua = __float_as_uint(a) + 0x8000u;
  unsigned int ub = __float_as_uint(b) + 0x8000u;
  return __builtin_amdgcn_perm(ub, ua, 0x07060302u);
}

// raw v_exp_f32 (2^x), single VALU transcendental; s_nop covers the
// trans->VALU dependency wait state.
static __device__ __forceinline__ float fexp2(float x) {
  float r;
  asm("v_exp_f32 %0, %1\n\ts_nop 0" : "=v"(r) : "v"(x));
  return r;
}

// async global->LDS DMA, 16 B per lane; lds base must be wave-uniform,
// HW writes lane i at ldsbase + i*16.
static __device__ __forceinline__ void gl2lds16(const unsigned short* g,
                                                unsigned short* l) {
  __builtin_amdgcn_global_load_lds(
      (const __attribute__((address_space(1))) void*)g,
      (__attribute__((address_space(3))) void*)l, 16, 0, 0);
}

// ---------------------------------------------------------------------------
// fp32 -> bf16 conversion for all 5 tensors + RoPE table gen, one launch.
// blockIdx.y: 0=x 1=Wq 2=Wk 3=Wv 4=Wo 5=rope tables
// ---------------------------------------------------------------------------
__global__ __launch_bounds__(256) void cvt_all(
    const float4* __restrict__ x,  const float4* __restrict__ wq,
    const float4* __restrict__ wk, const float4* __restrict__ wv,
    const float4* __restrict__ wo,
    ushort4* __restrict__ xb,  ushort4* __restrict__ wqb,
    ushort4* __restrict__ wkb, ushort4* __restrict__ wvb,
    ushort4* __restrict__ wob,
    const int* __restrict__ tokpos,
    float* __restrict__ ctab, float* __restrict__ stab) {
  int t = blockIdx.y;
  int i = blockIdx.x * 256 + threadIdx.x;
  if (t == 5) {
    if (i < 65536) {     // 2048 positions x 32 pair-freqs
      int s = i >> 5, f = i & 31;
      float inv = expf(-9.210340371976184f * (float)(2 * f) / 64.0f);
      float ang = (float)tokpos[s] * inv;
      ctab[i] = cosf(ang);
      stab[i] = sinf(ang);
    }
    return;
  }
  const float4* s = (t == 0) ? x : (t == 1) ? wq : (t == 2) ? wk : (t == 3) ? wv : wo;
  ushort4* d = (t == 0) ? xb : (t == 1) ? wqb : (t == 2) ? wkb : (t == 3) ? wvb : wob;
  int n4 = (t == 0) ? 1048576 : 262144;
  if (i < n4) {
    float4 v = s[i];
    ushort4 o;
    o.x = f2bf(v.x); o.y = f2bf(v.y); o.z = f2bf(v.z); o.w = f2bf(v.w);
    d[i] = o;
  }
}

// ---------------------------------------------------------------------------
// 128x128-tile GEMM body, m97 structure: global_load_lds width=16 staging into
// UNPADDED [128][64] LDS tiles with XOR chunk swizzle (LDS[r][c] holds global
// chunk c^(r&7); fragment reads fetch chunk (4ks+quad)^(l15&7) -> conflict-free
// per R7 measurement). C[128][128] = A[128x1024] * W^T, both row-major.
// ---------------------------------------------------------------------------
#define GEMM128_BODY(Aptr, Wptr, m0, n0)                                        \
  __shared__ __align__(16) unsigned short lA[128 * 64];                         \
  __shared__ __align__(16) unsigned short lB[128 * 64];                         \
  int tid = threadIdx.x;                                                        \
  int wave = tid >> 6, lane = tid & 63;                                         \
  int wm = wave >> 1, wn = wave & 1;                                            \
  int l15 = lane & 15, quad = lane >> 4;                                        \
  int srow = wave * 32 + (lane >> 3);  /* staging row (+p*8) */                 \
  int sch = lane & 7;                  /* staging 16B-chunk  */                 \
  int fsw = l15 & 7;                   /* fragment-read swizzle */              \
  floatx4 acc[4][4];                                                            \
  _Pragma("unroll") for (int m = 0; m < 4; ++m)                                 \
      _Pragma("unroll") for (int n = 0; n < 4; ++n)                             \
          acc[m][n] = (floatx4){0.f, 0.f, 0.f, 0.f};                            \
  for (int kt = 0; kt < 16; ++kt) {                                             \
    _Pragma("unroll") for (int p = 0; p < 4; ++p) {                             \
      int r = srow + p * 8;                                                     \
      int g = sch ^ (r & 7);                                                    \
      gl2lds16(Aptr + (size_t)(m0 + r) * 1024 + kt * 64 + g * 8,                \
               lA + (wave * 32 + p * 8) * 64);                                  \
      gl2lds16(Wptr + (size_t)(n0 + r) * 1024 + kt * 64 + g * 8,                \
               lB + (wave * 32 + p * 8) * 64);                                  \
    }                                                                           \
    __syncthreads();                                                            \
    _Pragma("unroll") for (int ks = 0; ks < 2; ++ks) {                          \
      short8 af[4], bf[4];                                                      \
      _Pragma("unroll") for (int m = 0; m < 4; ++m)                             \
          af[m] = *(const short8*)(lA + (wm * 64 + m * 16 + l15) * 64 +         \
                                   (((ks * 4 + quad) ^ fsw) * 8));              \
      _Pragma("unroll") for (int n = 0; n < 4; ++n)                             \
          bf[n] = *(const short8*)(lB + (wn * 64 + n * 16 + l15) * 64 +         \
                                   (((ks * 4 + quad) ^ fsw) * 8));              \
      _Pragma("unroll") for (int m = 0; m < 4; ++m)                             \
          _Pragma("unroll") for (int n = 0; n < 4; ++n)                         \
              acc[m][n] = __builtin_amdgcn_mfma_f32_16x16x32_bf16(              \
                  af[m], bf[n], acc[m][n], 0, 0, 0);                            \
    }                                                                           \
    __syncthreads();                                                            \
  }

// ---------------------------------------------------------------------------
// QKV projection, tiled MFMA GEMM + fused RoPE epilogue.
// Q pre-scaled by (1/sqrt(64))*log2(e) so attention uses raw v_exp_f32.
// Q,K bf16 [bh][s][64]; V transposed [bh][d][2048].
// ---------------------------------------------------------------------------
__global__ __launch_bounds__(256) void qkv_mfma(
    const unsigned short* __restrict__ X,
    const unsigned short* __restrict__ Wq,
    const unsigned short* __restrict__ Wk,
    const unsigned short* __restrict__ Wv,
    const float* __restrict__ ctab, const float* __restrict__ stab,
    unsigned short* __restrict__ Qo, unsigned short* __restrict__ Ko,
    unsigned short* __restrict__ Vo) {
  int mat = blockIdx.z;  // 0=q 1=k 2=v
  const unsigned short* W = (mat == 0) ? Wq : ((mat == 1) ? Wk : Wv);
  unsigned short* Out = (mat == 0) ? Qo : ((mat == 1) ? Ko : Vo);
  int m0 = blockIdx.x * 128, n0 = blockIdx.y * 128;

  GEMM128_BODY(X, W, m0, n0)

#pragma unroll
  for (int n = 0; n < 4; ++n) {
    int col = n0 + wn * 64 + n * 16 + l15;  // 0..1023
    int h = col >> 6;
    int d = col & 63;
    int pi = d >> 1;
    bool odd = (d & 1) != 0;
    size_t hb = (size_t)h * 2048 * 64;
#pragma unroll
    for (int m = 0; m < 4; ++m) {
      int row0 = m0 + wm * 64 + m * 16 + quad * 4;  // rows row0..row0+3
      int b = row0 >> 11;
      int s0 = row0 & 2047;
      size_t base = (size_t)b * 16 * 2048 * 64 + hb;
      if (mat == 2) {
        // V: packed b64 store along s (transposed layout [d][s])
        ushort4 pv;
        pv.x = f2bf(acc[m][n][0]);
        pv.y = f2bf(acc[m][n][1]);
        pv.z = f2bf(acc[m][n][2]);
        pv.w = f2bf(acc[m][n][3]);
        *(ushort4*)(Out + base + (size_t)d * 2048 + s0) = pv;
      } else {
#pragma unroll
        for (int i = 0; i < 4; ++i) {
          int s = s0 + i;
          float v = acc[m][n][i];
          float p = __shfl_xor(v, 1);
          float c = ctab[s * 32 + pi];
          float sn = stab[s * 32 + pi];
          float res = odd ? fmaf(p, sn, v * c) : fmaf(v, c, -p * sn);
          if (mat == 0) res *= 0.1803368801111204f;  // 0.125 * log2(e)
          Out[base + (size_t)s * 64 + d] = f2bf(res);
        }
      }
    }
  }
}

// ---------------------------------------------------------------------------
// Output projection: out = Oc @ Wo^T.  64x128 tiles -> 512 blocks (2/CU, so
// barrier drains overlap across blocks; the 128x128 version was 1 block/CU).
// Same DMA staging + XOR swizzle as GEMM128. fp32 store.
// ---------------------------------------------------------------------------
__global__ __launch_bounds__(256) void oproj_mfma(
    const unsigned short* __restrict__ A, const unsigned short* __restrict__ Wo,
    float* __restrict__ Out) {
  __shared__ __align__(16) unsigned short lA[64 * 64];
  __shared__ __align__(16) unsigned short lB[128 * 64];
  int tid = threadIdx.x;
  int wave = tid >> 6, lane = tid & 63;
  int l15 = lane & 15, quad = lane >> 4;
  int rsub = lane >> 3, sch = lane & 7;
  int fsw = l15 & 7;
  int m0 = blockIdx.x * 64, n0 = blockIdx.y * 128;

  floatx4 acc[4][2];
#pragma unroll
  for (int m = 0; m < 4; ++m)
#pragma unroll
    for (int n = 0; n < 2; ++n) acc[m][n] = (floatx4){0.f, 0.f, 0.f, 0.f};

  for (int kt = 0; kt < 16; ++kt) {
#pragma unroll
    for (int p = 0; p < 2; ++p) {  // lA: wave stages rows wave*16+p*8..+8
      int r = wave * 16 + p * 8 + rsub;
      int g = sch ^ (r & 7);
      gl2lds16(A + (size_t)(m0 + r) * 1024 + kt * 64 + g * 8,
               lA + (wave * 16 + p * 8) * 64);
    }
#pragma unroll
    for (int p = 0; p < 4; ++p) {  // lB: wave stages rows wave*32+p*8..+8
      int r = wave * 32 + p * 8 + rsub;
      int g = sch ^ (r & 7);
      gl2lds16(Wo + (size_t)(n0 + r) * 1024 + kt * 64 + g * 8,
               lB + (wave * 32 + p * 8) * 64);
    }
    __syncthreads();
#pragma unroll
    for (int ks = 0; ks < 2; ++ks) {
      int slot = ((ks * 4 + quad) ^ fsw) * 8;
      short8 af[4], bf[2];
#pragma unroll
      for (int m = 0; m < 4; ++m)
        af[m] = *(const short8*)(lA + (m * 16 + l15) * 64 + slot);
#pragma unroll
      for (int n = 0; n < 2; ++n)
        bf[n] = *(const short8*)(lB + (wave * 32 + n * 16 + l15) * 64 + slot);
#pragma unroll
      for (int m = 0; m < 4; ++m)
#pragma unroll
        for (int n = 0; n < 2; ++n)
          acc[m][n] = __builtin_amdgcn_mfma_f32_16x16x32_bf16(
              af[m], bf[n], acc[m][n], 0, 0, 0);
    }
    __syncthreads();
  }

#pragma unroll
  for (int m = 0; m < 4; ++m) {
#pragma unroll
    for (int n = 0; n < 2; ++n) {
      int col = n0 + wave * 32 + n * 16 + l15;
#pragma unroll
      for (int i = 0; i < 4; ++i) {
        int row = m0 + m * 16 + quad * 4 + i;
        Out[(size_t)row * 1024 + col] = acc[m][n][i];
      }
    }
  }
}

// ---------------------------------------------------------------------------
// Flash attention: R8 shape (256 thr / 4 waves / 16 q per wave, 16 waves/CU)
// + R9's VALU cuts (raw v_exp_f32, v_perm bf16 packing).
// Transposed-score form: per-lane q softmax (in-lane tree + 2 shfl_xor).
// K/V LDS: unpadded stride-64 with XOR chunk swizzle (conflict-free).
// Register-prefetch double buffering for K/V staging.
// Balance swizzle: co-resident blocks {id,id+256,id+512,id+768} get qtiles
// {x, 31-x, (15-x)&31, (16+x)&31} -> 66 tile-iters per CU for every x.
// ---------------------------------------------------------------------------
#define LPS 72  // lP row stride

__global__ __launch_bounds__(256) void attn_flash(
    const unsigned short* __restrict__ Q, const unsigned short* __restrict__ K,
    const unsigned short* __restrict__ Vt, unsigned short* __restrict__ Oc) {
  __shared__ __align__(16) unsigned short lK[64 * 64];   // [kj][d] swizzled
  __shared__ __align__(16) unsigned short lV[64 * 64];   // [d][kj] swizzled
  __shared__ unsigned short lP[4][16 * LPS];             // per-wave [q][kj]

  int tid = threadIdx.x;
  int wave = tid >> 6, lane = tid & 63;
  int l15 = lane & 15, quad = lane >> 4;

  int xb_ = blockIdx.x;          // 0..31
  int yb_ = blockIdx.y;          // 0..31
  int jb = yb_ >> 3, ib = yb_ & 7;
  int qtile;
  if (jb == 0)      qtile = xb_;
  else if (jb == 1) qtile = 31 - xb_;
  else if (jb == 2) qtile = (15 - xb_) & 31;
  else              qtile = (16 + xb_) & 31;
  int bh = ib * 4 + jb;

  size_t base = (size_t)bh * 2048 * 64;
  int qbase = qtile * 64;

  // Q rows as B-operand fragments (B[k=d][n=q]); q = wavebase + l15
  const unsigned short* qrow = Q + base + (size_t)(qbase + wave * 16 + l15) * 64;
  short8 qb0 = *(const short8*)(qrow + quad * 8);
  short8 qb1 = *(const short8*)(qrow + 32 + quad * 8);

  floatx4 o[4];          // O^T[d = n*16+quad*4+reg][q = l15]
  float m_i = -1e30f, l_i = 0.f;   // per-lane softmax state (q = l15)
#pragma unroll
  for (int n = 0; n < 4; ++n) o[n] = (floatx4){0.f, 0.f, 0.f, 0.f};

  // staging: thread covers rows r0,r1 (r1=r0+32, same &7), global chunk g
  int r0 = tid >> 3, g = tid & 7;
  int r1 = r0 + 32;
  int e0 = g * 8;                       // global element offset of chunk g
  int sl = (g ^ (r0 & 7)) * 8;          // swizzled LDS slot (element offset)
  int fsw = l15 & 7;                    // fragment-read swizzle
  int c0 = (quad ^ fsw) * 8;            // slot of global chunk quad
  int c1 = ((quad + 4) ^ fsw) * 8;      // slot of global chunk quad+4

  // prefetch kt=0
  const unsigned short* kp = K + base;
  const unsigned short* vp = Vt + base;
  short8 pk0 = *(const short8*)(kp + r0 * 64 + e0);
  short8 pk1 = *(const short8*)(kp + r1 * 64 + e0);
  short8 pv0 = *(const short8*)(vp + (size_t)r0 * 2048 + e0);
  short8 pv1 = *(const short8*)(vp + (size_t)r1 * 2048 + e0);

  for (int kt = 0; kt <= qtile; ++kt) {
    __syncthreads();   // all waves done reading lK/lV from previous iter
    *(short8*)(lK + r0 * 64 + sl) = pk0;
    *(short8*)(lK + r1 * 64 + sl) = pk1;
    *(short8*)(lV + r0 * 64 + sl) = pv0;
    *(short8*)(lV + r1 * 64 + sl) = pv1;
    __syncthreads();

    if (kt < qtile) {  // prefetch next tile; consumed at next iter's LDS write
      const unsigned short* kn = K + base + (size_t)(kt + 1) * 4096;
      const unsigned short* vn = Vt + base + (kt + 1) * 64;
      pk0 = *(const short8*)(kn + r0 * 64 + e0);
      pk1 = *(const short8*)(kn + r1 * 64 + e0);
      pv0 = *(const short8*)(vn + (size_t)r0 * 2048 + e0);
      pv1 = *(const short8*)(vn + (size_t)r1 * 2048 + e0);
    }

    // ---- S^T = K·Q^T : sc[sub][i] is score for kpos = sub*16+quad*4+i, q=l15
    float sc[4][4];
#pragma unroll
    for (int sub = 0; sub < 4; ++sub) {
      const unsigned short* kr = lK + (sub * 16 + l15) * 64;
      short8 a0 = *(const short8*)(kr + c0);
      short8 a1 = *(const short8*)(kr + c1);
      floatx4 s = {0.f, 0.f, 0.f, 0.f};
      s = __builtin_amdgcn_mfma_f32_16x16x32_bf16(a0, qb0, s, 0, 0, 0);
      s = __builtin_amdgcn_mfma_f32_16x16x32_bf16(a1, qb1, s, 0, 0, 0);
#pragma unroll
      for (int i = 0; i < 4; ++i) sc[sub][i] = s[i];
    }

    // ---- causal mask (diagonal tile only): k-within > q-within
    if (kt == qtile) {
      int qin = wave * 16 + l15;
#pragma unroll
      for (int sub = 0; sub < 4; ++sub)
#pragma unroll
        for (int i = 0; i < 4; ++i)
          if (sub * 16 + quad * 4 + i > qin) sc[sub][i] = -1e30f;
    }

    // ---- online softmax (log2 domain): in-lane tree + 2 cross-quad shuffles
    float mb = sc[0][0];
#pragma unroll
    for (int sub = 0; sub < 4; ++sub)
#pragma unroll
      for (int i = 0; i < 4; ++i) mb = fmaxf(mb, sc[sub][i]);
    mb = fmaxf(mb, __shfl_xor(mb, 16));
    mb = fmaxf(mb, __shfl_xor(mb, 32));

    float mn = fmaxf(m_i, mb);
    float al = fexp2(m_i - mn);
    m_i = mn;
    float rs = 0.f;
#pragma unroll
    for (int sub = 0; sub < 4; ++sub)
#pragma unroll
      for (int i = 0; i < 4; ++i) {
        float p = fexp2(sc[sub][i] - mn);
        sc[sub][i] = p;
        rs += p;
      }
    rs += __shfl_xor(rs, 16);
    rs += __shfl_xor(rs, 32);
    l_i = l_i * al + rs;

    // per-lane rescale of O^T columns (q = l15 matches softmax state)
#pragma unroll
    for (int n = 0; n < 4; ++n) {
      o[n][0] *= al; o[n][1] *= al; o[n][2] *= al; o[n][3] *= al;
    }

    // ---- P^T -> lP rows [q][k], packed pairs via v_perm
    unsigned short* pw = lP[wave] + l15 * LPS;
#pragma unroll
    for (int sub = 0; sub < 4; ++sub) {
      uint2 w;
      w.x = pk2bf(sc[sub][0], sc[sub][1]);
      w.y = pk2bf(sc[sub][2], sc[sub][3]);
      *(uint2*)(pw + sub * 16 + quad * 4) = w;
    }

    const unsigned short* pr = lP[wave] + l15 * LPS + quad * 8;
    short8 pa0 = *(const short8*)(pr);
    short8 pa1 = *(const short8*)(pr + 32);

    // ---- O^T += V^T·P^T : A = lV rows (d), B = lP rows (q)
#pragma unroll
    for (int n = 0; n < 4; ++n) {
      const unsigned short* vr = lV + (n * 16 + l15) * 64;
      short8 vb0 = *(const short8*)(vr + c0);
      short8 vb1 = *(const short8*)(vr + c1);
      o[n] = __builtin_amdgcn_mfma_f32_16x16x32_bf16(vb0, pa0, o[n], 0, 0, 0);
      o[n] = __builtin_amdgcn_mfma_f32_16x16x32_bf16(vb1, pa1, o[n], 0, 0, 0);
    }
  }

  // ---- epilogue: per-lane 1/l, packed b64 stores
  int b = bh >> 4, h = bh & 15;
  float inv = 1.f / l_i;
  int s = qbase + wave * 16 + l15;
  size_t orow = (size_t)(b * 2048 + s) * 1024 + h * 64;
#pragma unroll
  for (int n = 0; n < 4; ++n) {
    uint2 ov;
    ov.x = pk2bf(o[n][0] * inv, o[n][1] * inv);
    ov.y = pk2bf(o[n][2] * inv, o[n][3] * inv);
    *(uint2*)(Oc + orow + n * 16 + quad * 4) = ov;
  }
}

// ---------------------------------------------------------------------------
extern "C" void kernel_launch(void* const* d_in, const int* in_sizes, int n_in,
                              void* d_out, int out_size, void* d_ws, size_t ws_size,
                              hipStream_t stream) {
  const float* x  = (const float*)d_in[0];
  const int* tokpos = (const int*)d_in[1];
  const float* Wq = (const float*)d_in[2];
  const float* Wk = (const float*)d_in[3];
  const float* Wv = (const float*)d_in[4];
  const float* Wo = (const float*)d_in[5];
  float* out = (float*)d_out;

  float* ws = (float*)d_ws;
  float* ctab = ws;
  float* stab = ctab + 65536;
  unsigned short* u = (unsigned short*)(stab + 65536);
  unsigned short* Qb  = u;
  unsigned short* Kb  = Qb + 4194304;
  unsigned short* Vb  = Kb + 4194304;   // transposed [bh][d][s]
  unsigned short* Oc  = Vb + 4194304;
  unsigned short* xb  = Oc + 4194304;
  unsigned short* Wqb = xb + 4194304;
  unsigned short* Wkb = Wqb + 1048576;
  unsigned short* Wvb = Wkb + 1048576;
  unsigned short* Wob = Wvb + 1048576;

  cvt_all<<<dim3(4096, 6), 256, 0, stream>>>(
      (const float4*)x, (const float4*)Wq, (const float4*)Wk,
      (const float4*)Wv, (const float4*)Wo,
      (ushort4*)xb, (ushort4*)Wqb, (ushort4*)Wkb, (ushort4*)Wvb, (ushort4*)Wob,
      tokpos, ctab, stab);

  qkv_mfma<<<dim3(32, 8, 3), 256, 0, stream>>>(
      xb, Wqb, Wkb, Wvb, ctab, stab, Qb, Kb, Vb);
  attn_flash<<<dim3(32, 32), 256, 0, stream>>>(Qb, Kb, Vb, Oc);
  oproj_mfma<<<dim3(64, 8), 256, 0, stream>>>(Oc, Wob, out);
}